// Round 12
// baseline (268.361 us; speedup 1.0000x reference)
//
#include <hip/hip_runtime.h>

#define BATCH 2
#define SEQ   2048
#define CH    1280
#define NH    20
#define HD    64
#define BS    (BATCH*SEQ)
#define RK    4

typedef __attribute__((ext_vector_type(2)))  float floatx2;
typedef __attribute__((ext_vector_type(4)))  short bf16x4;
typedef __attribute__((ext_vector_type(8)))  short bf16x8;
typedef __attribute__((ext_vector_type(16))) float floatx16;

__device__ __forceinline__ floatx16 mfma32(bf16x8 a, bf16x8 b, floatx16 c) {
    return __builtin_amdgcn_mfma_f32_32x32x16_bf16(a, b, c, 0, 0, 0);
}
// K=8 variant (v_mfma_f32_32x32x8_bf16): A/B = 4 bf16/lane, k = 4*(lane>>5)+i.
__device__ __forceinline__ floatx16 mfma32k8(bf16x4 a, bf16x4 b, floatx16 c) {
    return __builtin_amdgcn_mfma_f32_32x32x8bf16_1k(a, b, c, 0, 0, 0);
}

// round-to-nearest-even f32 -> bf16
__device__ __forceinline__ unsigned short f2bf(float f) {
    unsigned int u = __float_as_uint(f);
    u += 0x7fffu + ((u >> 16) & 1u);
    return (unsigned short)(u >> 16);
}
// pack two f32 -> bf16x2 in one VGPR (round-half-up): 2 add + 1 perm
__device__ __forceinline__ unsigned int packbf(float hi, float lo) {
    unsigned int a = __float_as_uint(hi) + 0x8000u;
    unsigned int b = __float_as_uint(lo) + 0x8000u;
    return __builtin_amdgcn_perm(a, b, 0x07060302u);  // [a.hi16 : b.hi16]
}
__device__ __forceinline__ float fexp2(float x) {
#if __has_builtin(__builtin_amdgcn_exp2f)
    return __builtin_amdgcn_exp2f(x);
#else
    return exp2f(x);
#endif
}

// async 16B global -> LDS (DMA). LDS dest = wave-uniform base + lane*16.
__device__ __forceinline__ void cp16(const unsigned short* g, unsigned short* l) {
    __builtin_amdgcn_global_load_lds(
        (const __attribute__((address_space(1))) unsigned int*)g,
        (__attribute__((address_space(3))) unsigned int*)l, 16, 0, 0);
}

// ---------------------------------------------------------------------------
// Merged prep, float4-vectorized: fold LoRA into weights -> bf16; cast x.
// ---------------------------------------------------------------------------
#define F4_BLOCKS   (CH * CH / 1024)       // 1600 per weight
#define CAST_BLOCKS (BS * CH / 1024)       // 5120

__global__ __launch_bounds__(256) void prep(
    const float* __restrict__ x,
    const float* __restrict__ Wq, const float* __restrict__ Wk,
    const float* __restrict__ Wv, const float* __restrict__ Wo,
    const float* __restrict__ Aq, const float* __restrict__ Bq,
    const float* __restrict__ Ak, const float* __restrict__ Bk,
    const float* __restrict__ Av, const float* __restrict__ Bv,
    const float* __restrict__ Ao, const float* __restrict__ Bo,
    unsigned short* __restrict__ wq_bf, unsigned short* __restrict__ wk_bf,
    unsigned short* __restrict__ wv_bf, unsigned short* __restrict__ wo_bf,
    unsigned short* __restrict__ xb)
{
    const int bx = blockIdx.x;
    if (bx < 4 * F4_BLOCKS) {
        int which = bx / F4_BLOCKS;
        int e = ((bx % F4_BLOCKS) * 256 + threadIdx.x) * 4;
        int i = e / CH, j = e % CH;
        const float *W, *A, *Bm;
        unsigned short* o;
        if (which == 0)      { W = Wq; A = Aq; Bm = Bq; o = wq_bf; }
        else if (which == 1) { W = Wk; A = Ak; Bm = Bk; o = wk_bf; }
        else if (which == 2) { W = Wv; A = Av; Bm = Bv; o = wv_bf; }
        else                 { W = Wo; A = Ao; Bm = Bo; o = wo_bf; }
        float4 acc = *(const float4*)(W + e);
#pragma unroll
        for (int r = 0; r < RK; r++) {
            float bm = Bm[i * RK + r];
            float4 a4 = *(const float4*)(A + r * CH + j);
            acc.x += bm * a4.x; acc.y += bm * a4.y;
            acc.z += bm * a4.z; acc.w += bm * a4.w;
        }
        ushort4 ov;
        ov.x = f2bf(acc.x); ov.y = f2bf(acc.y);
        ov.z = f2bf(acc.z); ov.w = f2bf(acc.w);
        *(ushort4*)(o + e) = ov;
    } else {
        int idx = ((bx - 4 * F4_BLOCKS) * 256 + threadIdx.x) * 4;
        float4 v = *(const float4*)(x + idx);
        ushort4 o;
        o.x = f2bf(v.x); o.y = f2bf(v.y); o.z = f2bf(v.z); o.w = f2bf(v.w);
        *(ushort4*)(xb + idx) = o;
    }
}

// ---------------------------------------------------------------------------
// GEMM: out[m][n] = sum_k A[m][k]*B[n][k]. 128x128 tile, BK=64, 32x32x16
// MFMA. global_load_lds staging into XOR-swizzled LDS (phys = cc^(row&7)).
// mode 0: bf16 out (scaled). mode 1: f32 out + bias.
// mode 2: fused V transpose -> vt[(bh*HD+d)*SEQ + interleaved(s)].
// ---------------------------------------------------------------------------
__device__ __forceinline__ void gemm128(
    const unsigned short* __restrict__ A, const unsigned short* __restrict__ B,
    unsigned short* __restrict__ obf, float* __restrict__ of,
    const float* __restrict__ bias, float oscale, int mode,
    unsigned short* __restrict__ vt)
{
    __shared__ __align__(16) unsigned short smem[2 * 128 * 64];
    unsigned short* sa = smem;
    unsigned short* sb = smem + 128 * 64;
    const int tid = threadIdx.x;
    const int wav = tid >> 6, lane = tid & 63;
    const int n32 = lane & 31, half = lane >> 5;
    const int wr = wav >> 1, wc = wav & 1;
    const int M0 = blockIdx.y * 128, N0 = blockIdx.x * 128;

    const unsigned short* ga[4]; const unsigned short* gb[4];
    unsigned short* la[4]; unsigned short* lb[4];
#pragma unroll
    for (int g = 0; g < 4; g++) {
        int s = g * 256 + tid;
        int row = s >> 3, cc = (s & 7) ^ (row & 7);
        ga[g] = A + (size_t)(M0 + row) * CH + cc * 8;
        gb[g] = B + (size_t)(N0 + row) * CH + cc * 8;
        la[g] = sa + (size_t)(g * 256 + wav * 64) * 8;
        lb[g] = sb + (size_t)(g * 256 + wav * 64) * 8;
    }

    const int arow0 = wr * 64 + n32, brow0 = wc * 64 + n32;

    floatx16 acc[2][2];
#pragma unroll
    for (int mt = 0; mt < 2; mt++)
#pragma unroll
        for (int nt = 0; nt < 2; nt++)
#pragma unroll
            for (int r = 0; r < 16; r++) acc[mt][nt][r] = 0.f;

    for (int k0 = 0; k0 < CH; k0 += 64) {
#pragma unroll
        for (int g = 0; g < 4; g++) { cp16(ga[g], la[g]); cp16(gb[g], lb[g]); }
#pragma unroll
        for (int g = 0; g < 4; g++) { ga[g] += 64; gb[g] += 64; }
        __syncthreads();

        bf16x8 av[2][4], bv[2][4];
#pragma unroll
        for (int mt = 0; mt < 2; mt++) {
            const int ar = arow0 + mt * 32, br = brow0 + mt * 32;
#pragma unroll
            for (int ks = 0; ks < 4; ks++) {
                const int cc = ks * 2 + half;
                av[mt][ks] = *(const bf16x8*)(sa + ar * 64 + ((cc ^ (ar & 7)) << 3));
                bv[mt][ks] = *(const bf16x8*)(sb + br * 64 + ((cc ^ (br & 7)) << 3));
            }
        }
#pragma unroll
        for (int ks = 0; ks < 4; ks++)
#pragma unroll
            for (int mt = 0; mt < 2; mt++)
#pragma unroll
                for (int nt = 0; nt < 2; nt++)
                    acc[mt][nt] = mfma32(av[mt][ks], bv[nt][ks], acc[mt][nt]);
        __syncthreads();
    }

    if (mode == 2) {
        // fused V transpose: regs -> LDS [ch_local][s swizzled] (b64 units)
#pragma unroll
        for (int mt = 0; mt < 2; mt++) {
#pragma unroll
            for (int nt = 0; nt < 2; nt++) {
                const int dl = wc * 64 + nt * 32 + n32;
#pragma unroll
                for (int j = 0; j < 4; j++) {
                    const int u = wr * 16 + mt * 8 + 2 * j + half;
                    uint2 w;
                    w.x = packbf(acc[mt][nt][4 * j + 1], acc[mt][nt][4 * j + 0]);
                    w.y = packbf(acc[mt][nt][4 * j + 3], acc[mt][nt][4 * j + 2]);
                    *(uint2*)(smem + dl * 128 + ((u ^ n32) << 2)) = w;
                }
            }
        }
        __syncthreads();
        const int b = M0 >> 11;
        const int s_in = M0 & (SEQ - 1);
#pragma unroll
        for (int g = 0; g < 8; g++) {
            int cid = g * 256 + tid;
            int dl = cid >> 4, pc = cid & 15;
            int g32 = pc >> 2, p = (pc & 3) >> 1, hb = pc & 1;
            int u1 = 8 * g32 + 4 * p + hb;
            int sw = dl & 31;
            uint2 r1 = *(const uint2*)(smem + dl * 128 + ((u1 ^ sw) << 2));
            uint2 r2 = *(const uint2*)(smem + dl * 128 + (((u1 + 2) ^ sw) << 2));
            int ch = N0 + dl, h = ch >> 6, d = ch & 63;
            uint4 val; val.x = r1.x; val.y = r1.y; val.z = r2.x; val.w = r2.y;
            *(uint4*)(vt + (size_t)((b * NH + h) * HD + d) * SEQ + s_in + pc * 8) = val;
        }
        return;
    }

#pragma unroll
    for (int mt = 0; mt < 2; mt++) {
#pragma unroll
        for (int nt = 0; nt < 2; nt++) {
            const int col = N0 + wc * 64 + nt * 32 + n32;
            const float bv2 = (mode == 1) ? bias[col] : 0.f;
#pragma unroll
            for (int r = 0; r < 16; r++) {
                size_t row = (size_t)(M0 + wr * 64 + mt * 32 +
                                      (r & 3) + 8 * (r >> 2) + 4 * half);
                if (mode == 1) of[row * CH + col] = acc[mt][nt][r] + bv2;
                else           obf[row * CH + col] = f2bf(acc[mt][nt][r] * oscale);
            }
        }
    }
}

__global__ __launch_bounds__(256) void gemm_qkv(
    const unsigned short* __restrict__ xb,
    const unsigned short* __restrict__ wq, const unsigned short* __restrict__ wk,
    const unsigned short* __restrict__ wv,
    unsigned short* __restrict__ q, unsigned short* __restrict__ k,
    unsigned short* __restrict__ vt)
{
    const unsigned short* w = blockIdx.z == 0 ? wq : blockIdx.z == 1 ? wk : wv;
    unsigned short* o = blockIdx.z == 0 ? q : k;
    // q pre-scaled by 1/sqrt(64) * log2(e): softmax becomes a bare exp2
    float scale = blockIdx.z == 0 ? 0.18033688011112042f : 1.0f;
    int mode = blockIdx.z == 2 ? 2 : 0;
    gemm128(xb, w, o, nullptr, nullptr, scale, mode, vt);
}

__global__ __launch_bounds__(256) void gemm_o(
    const unsigned short* __restrict__ c_bf, const unsigned short* __restrict__ wo,
    const float* __restrict__ bias, float* __restrict__ out)
{
    gemm128(c_bf, wo, nullptr, out, bias, 1.0f, 1, nullptr);
}

// ---------------------------------------------------------------------------
// Key-split transposed flash attention. Grid (16, 40, 2) = 1280 blocks =
// exactly 5 blocks/CU (5 x 32KB = the full 160KB LDS pool, zero tail).
// Block (q0, bh, split) processes keys [split*1024, split*1024+1024) for the
// full 128-q tile: per-block staging:compute ratio identical to the R10
// kernel, iterations 16 -> 8. Fixed-max softmax => partials purely additive:
// write unnormalized bf16 O^T partial + f32 psum partial; merge() adds + norms.
// ---------------------------------------------------------------------------
__global__ __launch_bounds__(256, 5) void attention(
    const unsigned short* __restrict__ q, const unsigned short* __restrict__ k,
    const unsigned short* __restrict__ vt,
    unsigned short* __restrict__ po, float* __restrict__ ps)
{
    __shared__ __align__(16) unsigned short k_lds[128 * 64];  // [key][d] swz
    __shared__ __align__(16) unsigned short v_lds[64 * 128];  // [d][key-il] swz

    const int tid = threadIdx.x, wav = tid >> 6, lane = tid & 63;
    const int n32 = lane & 31, half = lane >> 5;
    const int q0 = blockIdx.x * 128;
    const int bh = blockIdx.y, b = bh / NH, h = bh % NH;
    const int split = blockIdx.z;
    const int t_base = split * (SEQ / 2);

    // Q as B-operand (held all kernel): frag f -> d = 16f + 8*half + j
    const size_t qrow = (size_t)(b * SEQ + q0 + wav * 32 + n32);
    bf16x8 qf[4];
#pragma unroll
    for (int f = 0; f < 4; f++)
        qf[f] = *(const bf16x8*)(q + qrow * CH + h * HD + f * 16 + half * 8);

    // staging bases (this split's key range)
    const int rowk = tid >> 3, cck = (tid & 7) ^ (rowk & 7);
    const int rowv = tid >> 4, ccv = (tid & 15) ^ (rowv & 15);
    const unsigned short* gk0 =
        k + (size_t)(b * SEQ + t_base + rowk) * CH + h * HD + cck * 8;
    const unsigned short* gv0 =
        vt + (size_t)(bh * HD + rowv) * SEQ + t_base + ccv * 8;
    unsigned short* lk0 = k_lds + (size_t)(wav * 64) * 8;
    unsigned short* lv0 = v_lds + (size_t)(wav * 64) * 8;

    floatx2 psv = {0.f, 0.f};
    floatx16 acc[2];
#pragma unroll
    for (int dt = 0; dt < 2; dt++)
#pragma unroll
        for (int r = 0; r < 16; r++) acc[dt][r] = 0.f;

    for (int t0 = 0; t0 < SEQ / 2; t0 += 128) {
#pragma unroll
        for (int g = 0; g < 4; g++) {
            cp16(gk0 + (size_t)g * 32 * CH, lk0 + g * 2048);
            cp16(gv0 + g * 16 * SEQ, lv0 + g * 2048);
        }
        gk0 += (size_t)128 * CH; gv0 += 128;
        __syncthreads();

#pragma unroll
        for (int kt = 0; kt < 4; kt++) {
            // S^T tile (32 keys x 32 q): A = K rows, B = Q row
            const int keyrow = kt * 32 + n32;
            const unsigned short* kr = k_lds + keyrow * 64;
            floatx16 st;
#pragma unroll
            for (int r = 0; r < 16; r++) st[r] = 0.f;
#pragma unroll
            for (int f = 0; f < 4; f++) {
                int phys = (2 * f + half) ^ (keyrow & 7);
                bf16x8 kf = *(const bf16x8*)(kr + phys * 8);
                st = mfma32(kf, qf[f], st);
            }

            // per 8-key group: exp2 + psum + pack + PV (short liveness)
#pragma unroll
            for (int pp = 0; pp < 2; pp++) {
                float p[8];
#pragma unroll
                for (int r = 0; r < 8; r++) p[r] = fexp2(st[8 * pp + r]);
                unsigned int pk[4];
#pragma unroll
                for (int j = 0; j < 4; j++) {
                    psv += (floatx2){p[2 * j], p[2 * j + 1]};
                    pk[j] = packbf(p[2 * j + 1], p[2 * j]);
                }
                union { unsigned int u[2]; bf16x4 v; } pb0, pb1;
                pb0.u[0] = pk[0]; pb0.u[1] = pk[1];
                pb1.u[0] = pk[2]; pb1.u[1] = pk[3];
#pragma unroll
                for (int dt = 0; dt < 2; dt++) {
                    const int drow = dt * 32 + n32;
                    int ct = kt * 4 + pp * 2 + half;
                    int phys = ct ^ (drow & 15);
                    union { bf16x8 v8; bf16x4 v4[2]; } vv;
                    vv.v8 = *(const bf16x8*)(v_lds + drow * 128 + phys * 8);
                    acc[dt] = mfma32k8(vv.v4[0], pb0.v, acc[dt]);
                    acc[dt] = mfma32k8(vv.v4[1], pb1.v, acc[dt]);
                }
            }
        }
        __syncthreads();
    }

    // ---- epilogue: write UNNORMALIZED partials ----
    float psum = psv.x + psv.y;
    float tot = psum + __shfl_xor(psum, 32, 64);   // both halves same value
    if (lane < 32)
        ps[(size_t)split * BATCH * NH * SEQ + (size_t)bh * SEQ +
           q0 + wav * 32 + n32] = tot;

    unsigned short* pob = po + (size_t)split * BS * CH;
    const size_t obase = qrow * CH + h * HD;
#pragma unroll
    for (int dt = 0; dt < 2; dt++) {
#pragma unroll
        for (int jj = 0; jj < 4; jj++) {
            int d = dt * 32 + 8 * jj + 4 * half;
            uint2 o2;
            o2.x = packbf(acc[dt][4 * jj + 1], acc[dt][4 * jj + 0]);
            o2.y = packbf(acc[dt][4 * jj + 3], acc[dt][4 * jj + 2]);
            *(uint2*)(pob + obase + d) = o2;
        }
    }
}

// ---------------------------------------------------------------------------
// Merge: c = (O0 + O1) / (ps0 + ps1), bf16 in/out, 8 elems/thread.
// ---------------------------------------------------------------------------
__device__ __forceinline__ unsigned int mergeword(unsigned int wa, unsigned int wb,
                                                  float rinv) {
    float lo = __uint_as_float(wa << 16) + __uint_as_float(wb << 16);
    float hi = __uint_as_float(wa & 0xffff0000u) + __uint_as_float(wb & 0xffff0000u);
    return packbf(hi * rinv, lo * rinv);
}

__global__ __launch_bounds__(256) void merge(
    const unsigned short* __restrict__ po, const float* __restrict__ ps,
    unsigned short* __restrict__ c_bf)
{
    const size_t idx = ((size_t)blockIdx.x * 256 + threadIdx.x) * 8;
    const int row = (int)(idx / CH);
    const int col = (int)(idx % CH);
    const int qq = row & (SEQ - 1);
    const int bh = (row >> 11) * NH + (col >> 6);
    const size_t psoff = (size_t)bh * SEQ + qq;
    float denom = ps[psoff] + ps[(size_t)BATCH * NH * SEQ + psoff];
    float rinv = __frcp_rn(denom);
    uint4 pa = *(const uint4*)(po + idx);
    uint4 pb = *(const uint4*)(po + (size_t)BS * CH + idx);
    uint4 o;
    o.x = mergeword(pa.x, pb.x, rinv);
    o.y = mergeword(pa.y, pb.y, rinv);
    o.z = mergeword(pa.z, pb.z, rinv);
    o.w = mergeword(pa.w, pb.w, rinv);
    *(uint4*)(c_bf + idx) = o;
}

// ---------------------------------------------------------------------------
extern "C" void kernel_launch(void* const* d_in, const int* in_sizes, int n_in,
                              void* d_out, int out_size, void* d_ws, size_t ws_size,
                              hipStream_t stream)
{
    const float* x  = (const float*)d_in[0];
    const float* Wq = (const float*)d_in[1];
    const float* Wk = (const float*)d_in[2];
    const float* Wv = (const float*)d_in[3];
    const float* Wo = (const float*)d_in[4];
    const float* bo = (const float*)d_in[5];
    const float* Aq = (const float*)d_in[6];
    const float* Bq = (const float*)d_in[7];
    const float* Ak = (const float*)d_in[8];
    const float* Bk = (const float*)d_in[9];
    const float* Av = (const float*)d_in[10];
    const float* Bv = (const float*)d_in[11];
    const float* Ao = (const float*)d_in[12];
    const float* Bo = (const float*)d_in[13];
    float* out = (float*)d_out;

    char* ws = (char*)d_ws;
    size_t off = 0;
    auto alloc = [&](size_t bytes) -> void* {
        void* p = ws + off; off += (bytes + 255) & ~(size_t)255; return p;
    };
    const size_t WB = (size_t)CH * CH, XB = (size_t)BS * CH;
    unsigned short* wq_bf = (unsigned short*)alloc(WB * 2);
    unsigned short* wk_bf = (unsigned short*)alloc(WB * 2);
    unsigned short* wv_bf = (unsigned short*)alloc(WB * 2);
    unsigned short* wo_bf = (unsigned short*)alloc(WB * 2);
    unsigned short* x_bf  = (unsigned short*)alloc(XB * 2);
    unsigned short* q_bf  = (unsigned short*)alloc(XB * 2);
    unsigned short* k_bf  = (unsigned short*)alloc(XB * 2);
    unsigned short* vt_bf = (unsigned short*)alloc(XB * 2);
    unsigned short* c_bf  = (unsigned short*)alloc(XB * 2);
    unsigned short* po    = (unsigned short*)alloc(2 * XB * 2);
    float*          psb   = (float*)alloc((size_t)2 * BATCH * NH * SEQ * 4);
    (void)ws_size; (void)n_in; (void)in_sizes; (void)out_size;

    prep<<<dim3(4 * F4_BLOCKS + CAST_BLOCKS), 256, 0, stream>>>(
        x, Wq, Wk, Wv, Wo, Aq, Bq, Ak, Bk, Av, Bv, Ao, Bo,
        wq_bf, wk_bf, wv_bf, wo_bf, x_bf);

    // q,k projections + V fused-transpose into vt
    gemm_qkv<<<dim3(CH / 128, BS / 128, 3), 256, 0, stream>>>(
        x_bf, wq_bf, wk_bf, wv_bf, q_bf, k_bf, vt_bf);

    attention<<<dim3(SEQ / 128, BATCH * NH, 2), 256, 0, stream>>>(
        q_bf, k_bf, vt_bf, po, psb);

    merge<<<dim3(XB / 2048), 256, 0, stream>>>(po, psb, c_bf);

    gemm_o<<<dim3(CH / 128, BS / 128), 256, 0, stream>>>(c_bf, wo_bf, bo, out);
}